// Round 2
// baseline (922.912 us; speedup 1.0000x reference)
//
#include <hip/hip_runtime.h>

#define EPSF 1e-8f

typedef __attribute__((ext_vector_type(8))) short bf16x8;
typedef __attribute__((ext_vector_type(4))) float f32x4;

constexpr int Nv     = 10000;  // N
constexpr int Ne     = 5000;   // E
constexpr int Dd     = 128;    // d
constexpr int NPAD   = 10016;  // 313*32
constexpr int EPAD   = 5120;   // 40*128
constexpr int KSTEPS = 313;    // NPAD/32
constexpr int KSPLIT = 12;     // 40*12 = 480 blocks = one residency round at 2 blocks/CU

__device__ __forceinline__ unsigned short f2bf_rne(float f) {
    unsigned int u = __builtin_bit_cast(unsigned int, f);
    u += 0x7fffu + ((u >> 16) & 1u);
    return (unsigned short)(u >> 16);
}

// dvis[n] = (Dv[n,n]+eps)^-1/2 (0 in pad) — hoists 1.28M strided diag reads to 10016
__global__ void prep_dv_kernel(const float* __restrict__ Dv, float* __restrict__ dvis) {
    int n = blockIdx.x * 256 + threadIdx.x;
    if (n < NPAD) dvis[n] = (n < Nv) ? rsqrtf(Dv[(size_t)n * (Nv + 1)] + EPSF) : 0.0f;
}

// Fst[c][n] = bf16(F[n,c] * dvis[n]); n-contiguous rows (B-operand layout).
// Also accumulates sum(F*F) -> out0 (each F element touched exactly once here).
__global__ void prep_fst_kernel(const float* __restrict__ F, const float* __restrict__ dvis,
                                short* __restrict__ Fst, float* __restrict__ out0) {
    int n = blockIdx.x * 256 + threadIdx.x;
    int c = blockIdx.y;
    float v = 0.0f;
    if (n < NPAD) {
        unsigned short b = 0;
        if (n < Nv) {
            float f = F[(size_t)n * Dd + c];          // F L3-resident (5 MB)
            v = f * f;
            b = f2bf_rne(f * dvis[n]);
        }
        Fst[(size_t)c * NPAD + n] = (short)b;
    }
    #pragma unroll
    for (int off = 32; off; off >>= 1) v += __shfl_down(v, off);
    if ((threadIdx.x & 63) == 0) atomicAdd(out0, v);
}

// Split-K GEMM: Mp[split][e][c] = sum_{n in split} H[n,e]*Fs[n,c]
// 512 threads, 128e x 128c tile, dbuf LDS, 1 barrier/step, prefetched H, no atomics.
// H staging is now COALESCED: thread (p = t>>5, b = t&31) loads float4 from rows
// n0+2p, n0+2p+1 at cols e0+4b — one wave instr = 2 full 512B rows (was 16-row x 32B
// scatter, 8 VMEM instr/thread/step -> now 2).
__global__ __launch_bounds__(512, 4)
void gemm_split_kernel(const float* __restrict__ H, const short* __restrict__ Fst,
                       float* __restrict__ Mp) {
    // Alds[buf][e][kk]: row stride 20 u32 = 80 B. Write addrs XOR-swizzled with
    // ((el>>3)&7)<<2 (u32 idx) to break the 16-way write conflict of the coalesced
    // mapping; b128 frag reads apply the same XOR (bits 2-4 only -> stays 16B-aligned,
    // read conflict class unchanged vs proven unswizzled layout).
    __shared__ unsigned int Alds[2][128 * 20];

    const int t   = threadIdx.x;
    const int w   = t >> 6;              // wave 0..7
    const int l   = t & 63;
    const int lm  = l & 15;
    const int q   = l >> 4;
    const int e0  = blockIdx.x * 128;
    const int we  = (w >> 1) * 32;       // wave e-offset {0,32,64,96}
    const int wc  = (w & 1) * 64;        // wave c-offset {0,64}
    const int spl = blockIdx.y;
    const int sb  = (spl * KSTEPS) / KSPLIT;
    const int se  = ((spl + 1) * KSTEPS) / KSPLIT;   // 26-27 steps/split

    const int p   = t >> 5;              // row-pair 0..15 (rows 2p, 2p+1 of the 32-chunk)
    const int bcl = t & 31;              // float4 col index (e-local = 4*bcl..4*bcl+3)
    const int ecol = e0 + 4 * bcl;       // Ne mult of 4 -> float4 fully valid iff ecol<Ne

    float4 hcur[2], hnxt[2];             // [row-in-pair]

    auto loadH = [&](int s, float4 (&h)[2]) {
        const int n = s * 32 + 2 * p;    // Nv even -> pair shares validity
        h[0] = make_float4(0.f, 0.f, 0.f, 0.f);
        h[1] = make_float4(0.f, 0.f, 0.f, 0.f);
        if (n < Nv && ecol < Ne) {
            h[0] = *(const float4*)(H + (size_t)n * Ne + ecol);
            h[1] = *(const float4*)(H + (size_t)(n + 1) * Ne + ecol);
        }
    };
    auto writeLDS = [&](int buf, float4 (&h)[2]) {
        const float a0[4] = {h[0].x, h[0].y, h[0].z, h[0].w};
        const float a1[4] = {h[1].x, h[1].y, h[1].z, h[1].w};
        #pragma unroll
        for (int j = 0; j < 4; ++j) {
            const int el = 4 * bcl + j;
            unsigned int wv = (unsigned int)f2bf_rne(a0[j]) | ((unsigned int)f2bf_rne(a1[j]) << 16);
            const int idx = (el * 20 + p) ^ (((el >> 3) & 7) << 2);
            Alds[buf][idx] = wv;         // row el, kk = 2p, 2p+1
        }
    };

    f32x4 acc[2][4];
    #pragma unroll
    for (int a = 0; a < 2; ++a)
        #pragma unroll
        for (int b = 0; b < 4; ++b) acc[a][b] = (f32x4){0.f, 0.f, 0.f, 0.f};

    loadH(sb, hcur);
    writeLDS(0, hcur);
    __syncthreads();

    for (int s = sb; s < se; ++s) {
        const int buf = (s - sb) & 1;
        const int n0  = s * 32;

        if (s + 1 < se) loadH(s + 1, hnxt);   // prefetch next K-chunk (overlaps MFMA)

        bf16x8 Bf[4];                          // B frags direct from L2-hot Fst
        #pragma unroll
        for (int cb = 0; cb < 4; ++cb) {
            const int c = wc + cb * 16 + lm;
            Bf[cb] = *(const bf16x8*)(Fst + (size_t)c * NPAD + n0 + q * 8);
        }
        bf16x8 Af[2];
        #pragma unroll
        for (int eb = 0; eb < 2; ++eb) {
            const int el = we + eb * 16 + lm;
            const int boff = (el * 80 + q * 16) ^ (((el >> 3) & 7) << 4);
            Af[eb] = *(const bf16x8*)((const char*)Alds[buf] + boff);
        }

        #pragma unroll
        for (int cb = 0; cb < 4; ++cb)
            #pragma unroll
            for (int eb = 0; eb < 2; ++eb)
                acc[eb][cb] = __builtin_amdgcn_mfma_f32_16x16x32_bf16(
                    Af[eb], Bf[cb], acc[eb][cb], 0, 0, 0);

        if (s + 1 < se) writeLDS(buf ^ 1, hnxt);  // fill other buffer
        __syncthreads();                           // single barrier per step
    }

    // epilogue: C/D layout col = lane&15, row = quad*4 + reg; plain coalesced stores
    float* dst = Mp + (size_t)spl * EPAD * 128;
    #pragma unroll
    for (int eb = 0; eb < 2; ++eb) {
        #pragma unroll
        for (int cb = 0; cb < 4; ++cb) {
            const int c = wc + cb * 16 + lm;
            #pragma unroll
            for (int r = 0; r < 4; ++r) {
                const int el = we + eb * 16 + q * 4 + r;
                dst[(size_t)(e0 + el) * 128 + c] = acc[eb][cb][r];
            }
        }
    }
}

// S = sum_e de_inv[e]*||sum_split Mp[.,e,:]||^2 -> ws0[1]  (de_inv folded in)
__global__ void reduce_m_kernel(const float* __restrict__ Mp, const float* __restrict__ De,
                                float* __restrict__ outS) {
    int gid = blockIdx.x * 256 + threadIdx.x;   // 640*256 = 163840 = EPAD*32
    int e   = gid >> 5;
    int c4  = (gid & 31) * 4;
    float de_inv = (e < Ne) ? 1.0f / (De[(size_t)e * (Ne + 1)] + EPSF) : 0.0f;  // wave-broadcast
    float4 m = {0.f, 0.f, 0.f, 0.f};
    #pragma unroll
    for (int sp = 0; sp < KSPLIT; ++sp) {
        float4 p = *(const float4*)(Mp + (size_t)sp * EPAD * 128 + (size_t)e * 128 + c4);
        m.x += p.x; m.y += p.y; m.z += p.z; m.w += p.w;
    }
    float sum = de_inv * (m.x*m.x + m.y*m.y + m.z*m.z + m.w*m.w);
    #pragma unroll
    for (int off = 32; off; off >>= 1) sum += __shfl_down(sum, off);
    if ((threadIdx.x & 63) == 0) atomicAdd(outS, sum);
}

__global__ void final_kernel(const float* __restrict__ ws0, float* __restrict__ out) {
    out[0] = (ws0[0] - ws0[1]) * (1.0f / (float)Nv);
}

extern "C" void kernel_launch(void* const* d_in, const int* in_sizes, int n_in,
                              void* d_out, int out_size, void* d_ws, size_t ws_size,
                              hipStream_t stream) {
    (void)in_sizes; (void)n_in; (void)out_size; (void)ws_size;
    const float* F  = (const float*)d_in[0];
    const float* H  = (const float*)d_in[1];
    const float* Dv = (const float*)d_in[2];
    const float* De = (const float*)d_in[3];
    float* out = (float*)d_out;

    // ws layout: ws0(16 f) | dvis[NPAD] | Mp[KSPLIT*EPAD*128] | Fst bf16[128*NPAD]
    float* ws0  = (float*)d_ws;
    float* dvis = ws0 + 16;
    float* Mp   = dvis + NPAD;                       // offset 40128 B (16B-aligned)
    short* Fst  = (short*)(Mp + (size_t)KSPLIT * EPAD * 128);

    hipMemsetAsync(ws0, 0, 64, stream);              // only the two scalar accumulators

    prep_dv_kernel <<<(NPAD + 255) / 256, 256, 0, stream>>>(Dv, dvis);
    prep_fst_kernel<<<dim3((NPAD + 255) / 256, 128), 256, 0, stream>>>(F, dvis, Fst, ws0);
    gemm_split_kernel<<<dim3(EPAD / 128, KSPLIT), 512, 0, stream>>>(H, Fst, Mp);
    reduce_m_kernel<<<640, 256, 0, stream>>>(Mp, De, ws0 + 1);
    final_kernel   <<<1, 1, 0, stream>>>(ws0, out);
}

// Round 3
// 617.823 us; speedup vs baseline: 1.4938x; 1.4938x over previous
//
#include <hip/hip_runtime.h>

#define EPSF 1e-8f

typedef __attribute__((ext_vector_type(8))) short bf16x8;
typedef __attribute__((ext_vector_type(4))) float f32x4;

constexpr int Nv     = 10000;  // N
constexpr int Ne     = 5000;   // E
constexpr int Dd     = 128;    // d
constexpr int NPAD   = 10016;  // 313*32
constexpr int EPAD   = 5120;   // 40*128
constexpr int KSTEPS = 313;    // NPAD/32
constexpr int KSPLIT = 12;     // 40*12 = 480 blocks = one residency round at 2 blocks/CU
constexpr int NBLK_P = 313;    // prep_fst blocks (= pFF partials)
constexpr int NBLK_R = 640;    // reduce_m blocks (= pS partials)

__device__ __forceinline__ unsigned short f2bf_rne(float f) {
    unsigned int u = __builtin_bit_cast(unsigned int, f);
    u += 0x7fffu + ((u >> 16) & 1u);
    return (unsigned short)(u >> 16);
}

// dvis[n] = (Dv[n,n]+eps)^-1/2 (0 in pad) — hoists 1.28M strided diag reads to 10016
__global__ void prep_dv_kernel(const float* __restrict__ Dv, float* __restrict__ dvis) {
    int n = blockIdx.x * 256 + threadIdx.x;
    if (n < NPAD) dvis[n] = (n < Nv) ? rsqrtf(Dv[(size_t)n * (Nv + 1)] + EPSF) : 0.0f;
}

// Coalesced transposing prep: reads F as float4 (one touch), LDS-transposes a
// 32n x 128c tile, writes Fst[c][n] packed as u32 bf16-pairs. Folds sum(F*F) into
// one partial store per block (NO contended atomics — round-2's 20480 same-address
// atomicAdds serialized at ~14ns each = 279us).
__global__ __launch_bounds__(256)
void prep_fst_kernel(const float* __restrict__ F, const float* __restrict__ dvis,
                     short* __restrict__ Fst, float* __restrict__ pFF) {
    __shared__ float T[128][33];     // [c][n_local], pad 33: writes 4-way, reads 2-way (free)
    __shared__ float red[4];
    const int t  = threadIdx.x;
    const int n0 = blockIdx.x * 32;  // 313*32 = 10016 = NPAD exactly

    float acc = 0.0f;
    #pragma unroll
    for (int p = 0; p < 4; ++p) {
        const int flat = (p * 256 + t) * 4;   // 0..4095 over the 32x128 tile
        const int nl   = flat >> 7;
        const int c    = flat & 127;
        const int n    = n0 + nl;
        float4 f = make_float4(0.f, 0.f, 0.f, 0.f);
        float  s = 0.0f;
        if (n < Nv) {
            f = *(const float4*)(F + (size_t)n * Dd + c);   // fully coalesced
            s = dvis[n];                                    // wave-broadcast (32 lanes share n)
        }
        acc += f.x*f.x + f.y*f.y + f.z*f.z + f.w*f.w;
        T[c + 0][nl] = f.x * s;
        T[c + 1][nl] = f.y * s;
        T[c + 2][nl] = f.z * s;
        T[c + 3][nl] = f.w * s;
    }
    __syncthreads();

    // pack & write: thread t -> c-row t>>1, n-half t&1; 8 contiguous u32 (32B) per thread
    {
        const int c = t >> 1, half = t & 1;
        unsigned int* dst = (unsigned int*)Fst + ((size_t)c * NPAD + n0) / 2 + half * 8;
        #pragma unroll
        for (int jj = 0; jj < 8; ++jj) {
            const int k = half * 16 + 2 * jj;
            dst[jj] = (unsigned int)f2bf_rne(T[c][k]) | ((unsigned int)f2bf_rne(T[c][k + 1]) << 16);
        }
    }

    // block-reduce acc -> one partial per block
    #pragma unroll
    for (int off = 32; off; off >>= 1) acc += __shfl_down(acc, off);
    if ((t & 63) == 0) red[t >> 6] = acc;
    __syncthreads();
    if (t == 0) pFF[blockIdx.x] = red[0] + red[1] + red[2] + red[3];
}

// Split-K GEMM: Mp[split][e][c] = sum_{n in split} H[n,e]*Fs[n,c]
// 512 threads, 128e x 128c tile, dbuf LDS, 1 barrier/step, prefetched H, no atomics.
// H staging COALESCED: thread (p=t>>5, b=t&31) loads float4 from rows n0+2p, n0+2p+1
// at cols e0+4b — one wave instr = 2 full 512B rows.
__global__ __launch_bounds__(512, 4)
void gemm_split_kernel(const float* __restrict__ H, const short* __restrict__ Fst,
                       float* __restrict__ Mp) {
    // Alds[buf][e][kk]: row stride 20 u32 = 80 B. Write addrs XOR-swizzled with
    // ((el>>3)&7)<<2 (u32 idx) to break the 16-way write conflict of the coalesced
    // mapping; b128 frag reads apply the same XOR (bits 2-4 only -> stays 16B-aligned).
    __shared__ unsigned int Alds[2][128 * 20];

    const int t   = threadIdx.x;
    const int w   = t >> 6;              // wave 0..7
    const int l   = t & 63;
    const int lm  = l & 15;
    const int q   = l >> 4;
    const int e0  = blockIdx.x * 128;
    const int we  = (w >> 1) * 32;       // wave e-offset {0,32,64,96}
    const int wc  = (w & 1) * 64;        // wave c-offset {0,64}
    const int spl = blockIdx.y;
    const int sb  = (spl * KSTEPS) / KSPLIT;
    const int se  = ((spl + 1) * KSTEPS) / KSPLIT;   // 26-27 steps/split

    const int p    = t >> 5;             // row-pair 0..15 (rows 2p, 2p+1 of the 32-chunk)
    const int bcl  = t & 31;             // float4 col index
    const int ecol = e0 + 4 * bcl;

    float4 hcur[2], hnxt[2];             // [row-in-pair]

    auto loadH = [&](int s, float4 (&h)[2]) {
        const int n = s * 32 + 2 * p;    // Nv even -> pair shares validity
        h[0] = make_float4(0.f, 0.f, 0.f, 0.f);
        h[1] = make_float4(0.f, 0.f, 0.f, 0.f);
        if (n < Nv && ecol < Ne) {
            h[0] = *(const float4*)(H + (size_t)n * Ne + ecol);
            h[1] = *(const float4*)(H + (size_t)(n + 1) * Ne + ecol);
        }
    };
    auto writeLDS = [&](int buf, float4 (&h)[2]) {
        const float a0[4] = {h[0].x, h[0].y, h[0].z, h[0].w};
        const float a1[4] = {h[1].x, h[1].y, h[1].z, h[1].w};
        #pragma unroll
        for (int j = 0; j < 4; ++j) {
            const int el = 4 * bcl + j;
            unsigned int wv = (unsigned int)f2bf_rne(a0[j]) | ((unsigned int)f2bf_rne(a1[j]) << 16);
            const int idx = (el * 20 + p) ^ (((el >> 3) & 7) << 2);
            Alds[buf][idx] = wv;         // row el, kk = 2p, 2p+1
        }
    };

    f32x4 acc[2][4];
    #pragma unroll
    for (int a = 0; a < 2; ++a)
        #pragma unroll
        for (int b = 0; b < 4; ++b) acc[a][b] = (f32x4){0.f, 0.f, 0.f, 0.f};

    loadH(sb, hcur);
    writeLDS(0, hcur);
    __syncthreads();

    for (int s = sb; s < se; ++s) {
        const int buf = (s - sb) & 1;
        const int n0  = s * 32;

        if (s + 1 < se) loadH(s + 1, hnxt);   // prefetch next K-chunk (overlaps MFMA)

        bf16x8 Bf[4];                          // B frags direct from L2-hot Fst
        #pragma unroll
        for (int cb = 0; cb < 4; ++cb) {
            const int c = wc + cb * 16 + lm;
            Bf[cb] = *(const bf16x8*)(Fst + (size_t)c * NPAD + n0 + q * 8);
        }
        bf16x8 Af[2];
        #pragma unroll
        for (int eb = 0; eb < 2; ++eb) {
            const int el = we + eb * 16 + lm;
            const int boff = (el * 80 + q * 16) ^ (((el >> 3) & 7) << 4);
            Af[eb] = *(const bf16x8*)((const char*)Alds[buf] + boff);
        }

        #pragma unroll
        for (int cb = 0; cb < 4; ++cb)
            #pragma unroll
            for (int eb = 0; eb < 2; ++eb)
                acc[eb][cb] = __builtin_amdgcn_mfma_f32_16x16x32_bf16(
                    Af[eb], Bf[cb], acc[eb][cb], 0, 0, 0);

        if (s + 1 < se) writeLDS(buf ^ 1, hnxt);  // fill other buffer
        __syncthreads();                           // single barrier per step
    }

    // epilogue: C/D layout col = lane&15, row = quad*4 + reg; plain coalesced stores
    float* dst = Mp + (size_t)spl * EPAD * 128;
    #pragma unroll
    for (int eb = 0; eb < 2; ++eb) {
        #pragma unroll
        for (int cb = 0; cb < 4; ++cb) {
            const int c = wc + cb * 16 + lm;
            #pragma unroll
            for (int r = 0; r < 4; ++r) {
                const int el = we + eb * 16 + q * 4 + r;
                dst[(size_t)(e0 + el) * 128 + c] = acc[eb][cb][r];
            }
        }
    }
}

// S partials: pS[blk] = sum_{e,c in blk} de_inv[e]*||sum_split Mp[.,e,:]||^2 (no atomics)
__global__ void reduce_m_kernel(const float* __restrict__ Mp, const float* __restrict__ De,
                                float* __restrict__ pS) {
    __shared__ float red[4];
    int gid = blockIdx.x * 256 + threadIdx.x;   // 640*256 = 163840 = EPAD*32
    int e   = gid >> 5;
    int c4  = (gid & 31) * 4;
    float de_inv = (e < Ne) ? 1.0f / (De[(size_t)e * (Ne + 1)] + EPSF) : 0.0f;  // wave-broadcast
    float4 m = {0.f, 0.f, 0.f, 0.f};
    #pragma unroll
    for (int sp = 0; sp < KSPLIT; ++sp) {
        float4 p = *(const float4*)(Mp + (size_t)sp * EPAD * 128 + (size_t)e * 128 + c4);
        m.x += p.x; m.y += p.y; m.z += p.z; m.w += p.w;
    }
    float sum = de_inv * (m.x*m.x + m.y*m.y + m.z*m.z + m.w*m.w);
    #pragma unroll
    for (int off = 32; off; off >>= 1) sum += __shfl_down(sum, off);
    if ((threadIdx.x & 63) == 0) red[threadIdx.x >> 6] = sum;
    __syncthreads();
    if (threadIdx.x == 0) pS[blockIdx.x] = red[0] + red[1] + red[2] + red[3];
}

// out = (sum pFF - sum pS) / N  — single block, deterministic, atomic-free
__global__ void final_kernel(const float* __restrict__ pFF, const float* __restrict__ pS,
                             float* __restrict__ out) {
    __shared__ float red[4];
    float v = 0.0f;
    for (int i = threadIdx.x; i < NBLK_P; i += 256) v += pFF[i];
    for (int i = threadIdx.x; i < NBLK_R; i += 256) v -= pS[i];
    #pragma unroll
    for (int off = 32; off; off >>= 1) v += __shfl_down(v, off);
    if ((threadIdx.x & 63) == 0) red[threadIdx.x >> 6] = v;
    __syncthreads();
    if (threadIdx.x == 0) out[0] = (red[0] + red[1] + red[2] + red[3]) * (1.0f / (float)Nv);
}

extern "C" void kernel_launch(void* const* d_in, const int* in_sizes, int n_in,
                              void* d_out, int out_size, void* d_ws, size_t ws_size,
                              hipStream_t stream) {
    (void)in_sizes; (void)n_in; (void)out_size; (void)ws_size;
    const float* F  = (const float*)d_in[0];
    const float* H  = (const float*)d_in[1];
    const float* Dv = (const float*)d_in[2];
    const float* De = (const float*)d_in[3];
    float* out = (float*)d_out;

    // ws layout: pFF[313] pS[640] (padded to 1024 f) | dvis[NPAD] | Mp | Fst
    float* pFF  = (float*)d_ws;
    float* pS   = pFF + NBLK_P;
    float* dvis = pFF + 1024;
    float* Mp   = dvis + NPAD;                       // byte offset 44160 (16B-aligned)
    short* Fst  = (short*)(Mp + (size_t)KSPLIT * EPAD * 128);

    prep_dv_kernel <<<(NPAD + 255) / 256, 256, 0, stream>>>(Dv, dvis);
    prep_fst_kernel<<<NBLK_P, 256, 0, stream>>>(F, dvis, Fst, pFF);
    gemm_split_kernel<<<dim3(EPAD / 128, KSPLIT), 512, 0, stream>>>(H, Fst, Mp);
    reduce_m_kernel<<<NBLK_R, 256, 0, stream>>>(Mp, De, pS);
    final_kernel   <<<1, 256, 0, stream>>>(pFF, pS, out);
}